// Round 5
// baseline (309.685 us; speedup 1.0000x reference)
//
#include <hip/hip_runtime.h>

typedef unsigned short u16t;
typedef short bf16x8 __attribute__((ext_vector_type(8)));
typedef float f32x4 __attribute__((ext_vector_type(4)));

#define T_SEQ 4096
#define NH    12
#define HD    64
#define C3    2304
#define CDIM  768
#define STRIP_KV 512

__device__ __forceinline__ float bf2f(u16t u) {
  union { unsigned int i; float f; } c; c.i = ((unsigned int)u) << 16; return c.f;
}
__device__ __forceinline__ u16t f2bf(float f) {
  union { float f; unsigned int i; } c; c.f = f;
  unsigned int u = c.i;
  u += 0x7fffu + ((u >> 16) & 1u);   // RNE
  return (u16t)(u >> 16);
}
__device__ __forceinline__ void gload16(const u16t* g, u16t* l) {
  __builtin_amdgcn_global_load_lds((const __attribute__((address_space(1))) void*)g,
                                   (__attribute__((address_space(3))) void*)l,
                                   16, 0, 0);
}

// ---------------------------------------------------------------------------
// Input-dtype detector (1 = fp32 inputs, 0 = bf16 inputs).
// ---------------------------------------------------------------------------
__global__ void detect_dtype(const u16t* __restrict__ x, int* __restrict__ flag) {
  __shared__ int cnt[256];
  int c = 0;
  for (int i = threadIdx.x; i < 4096; i += 256) {
    unsigned e = (x[2 * i] >> 7) & 0xFFu;
    c += (e < 112u || e > 136u) ? 1 : 0;
  }
  cnt[threadIdx.x] = c;
  __syncthreads();
  if (threadIdx.x == 0) {
    int s = 0;
    for (int i = 0; i < 256; ++i) s += cnt[i];
    *flag = (s > 2048) ? 1 : 0;
  }
}

__global__ __launch_bounds__(256) void convert_to_bf16(const void* __restrict__ in,
                                                       u16t* __restrict__ out, int n,
                                                       const int* __restrict__ flag) {
  const bool f32 = (*flag != 0);
  int i = blockIdx.x * 256 + threadIdx.x;
  const int stride = gridDim.x * 256;
  if (f32) {
    const float* p = (const float*)in;
    for (; i < n; i += stride) out[i] = f2bf(p[i]);
  } else {
    const u16t* p = (const u16t*)in;
    for (; i < n; i += stride) out[i] = p[i];
  }
}

__global__ __launch_bounds__(256) void transpose_to_bf16(const void* __restrict__ in,
                                                         u16t* __restrict__ out,
                                                         int R, int Cc,
                                                         const int* __restrict__ flag) {
  __shared__ u16t tile[32][33];
  const bool f32 = (*flag != 0);
  const int tx = threadIdx.x, ty = threadIdx.y;       // block (32,8)
  const int c0 = blockIdx.x * 32, r0 = blockIdx.y * 32;
#pragma unroll
  for (int i = 0; i < 32; i += 8) {
    const size_t idx = (size_t)(r0 + ty + i) * Cc + c0 + tx;
    tile[ty + i][tx] = f32 ? f2bf(((const float*)in)[idx]) : ((const u16t*)in)[idx];
  }
  __syncthreads();
#pragma unroll
  for (int i = 0; i < 32; i += 8)
    out[(size_t)(c0 + ty + i) * R + r0 + tx] = tile[tx][ty + i];
}

// ---------------------------------------------------------------------------
// C[M,N] = A[M,K]*B[K,N] + bias[N]; Bt row-major [N][K]; 128x128 tile, BK=32.
// ---------------------------------------------------------------------------
__global__ __launch_bounds__(256) void gemm_bt_bias(
    const u16t* __restrict__ A, const u16t* __restrict__ Bt,
    const void* __restrict__ bias, void* __restrict__ Cout,
    int M, int N, int K, const int* __restrict__ flag, int follow_flag) {
  __shared__ u16t lA[128 * 32];
  __shared__ u16t lB[128 * 32];
  const bool f32io = (*flag != 0);
  const int t = threadIdx.x;
  const int lane = t & 63;
  const int wid  = t >> 6;
  const int quad = lane >> 4, l16 = lane & 15;
  const int m0 = blockIdx.y * 128, n0 = blockIdx.x * 128;
  const int wm = (wid >> 1) * 64, wn = (wid & 1) * 64;

  f32x4 acc[4][4];
#pragma unroll
  for (int i = 0; i < 4; ++i)
#pragma unroll
    for (int j = 0; j < 4; ++j) acc[i][j] = (f32x4){0.f, 0.f, 0.f, 0.f};

  for (int k0 = 0; k0 < K; k0 += 32) {
    {
      int e = t;
      gload16(A  + (size_t)(m0 + (e >> 2)) * K + k0 + (e & 3) * 8, &lA[e * 8]);
      gload16(Bt + (size_t)(n0 + (e >> 2)) * K + k0 + (e & 3) * 8, &lB[e * 8]);
      e = 256 + t;
      gload16(A  + (size_t)(m0 + (e >> 2)) * K + k0 + (e & 3) * 8, &lA[e * 8]);
      gload16(Bt + (size_t)(n0 + (e >> 2)) * K + k0 + (e & 3) * 8, &lB[e * 8]);
    }
    __syncthreads();
    bf16x8 af[4], bfr[4];
#pragma unroll
    for (int i = 0; i < 4; ++i)
      af[i] = *(const bf16x8*)&lA[(wm + i * 16 + l16) * 32 + quad * 8];
#pragma unroll
    for (int i = 0; i < 4; ++i)
      bfr[i] = *(const bf16x8*)&lB[(wn + i * 16 + l16) * 32 + quad * 8];
#pragma unroll
    for (int i = 0; i < 4; ++i)
#pragma unroll
      for (int j = 0; j < 4; ++j)
        acc[i][j] = __builtin_amdgcn_mfma_f32_16x16x32_bf16(af[i], bfr[j], acc[i][j], 0, 0, 0);
    __syncthreads();
  }

  const bool out_f32 = (follow_flag != 0) && f32io;
#pragma unroll
  for (int j = 0; j < 4; ++j) {
    const int col = n0 + wn + j * 16 + l16;
    const float bv = f32io ? ((const float*)bias)[col] : bf2f(((const u16t*)bias)[col]);
#pragma unroll
    for (int i = 0; i < 4; ++i) {
      const int rowb = m0 + wm + i * 16 + quad * 4;
#pragma unroll
      for (int r = 0; r < 4; ++r) {
        const float val = acc[i][j][r] + bv;
        const size_t idx = (size_t)(rowb + r) * N + col;
        if (out_f32) ((float*)Cout)[idx] = val;
        else         ((u16t*)Cout)[idx] = f2bf(val);
      }
    }
  }
}

// ---------------------------------------------------------------------------
// Split-KV causal attention, UNNORMALIZED exp2 softmax, register-carried
// prefetch pipeline.  One block = one 512-wide KV strip of one 128-row Q tile
// of one head; grid (8,32,12), heavy q-tiles first.
//
// Pipeline per kv tile: global loads for tile i+1 land in VGPRs before the
// top barrier (vmcnt wait falls AFTER compute); ds_writes of those regs run
// post-compute behind the second barrier.  Single LDS buffer set.
//
// LDS strides are 80 u16 (dword-stride 40 == 8 mod 32, rows 16B-aligned) and
// V/P columns are XOR-swizzled so all b128 fragment reads and b64 writes hit
// the bank floor (verified by bank arithmetic; see session notes).
// Total LDS = 10240+10240+20480 = 40960 B -> exactly 4 blocks/CU.
// ---------------------------------------------------------------------------
#define KSTR 80
#define VSTR 80
#define PSTR 80

__global__ __launch_bounds__(256, 4) void attn_partial(const u16t* __restrict__ qkv,
                                                       float* __restrict__ accO,
                                                       float* __restrict__ accL) {
  const int qt = 31 - (int)blockIdx.y;              // heavy q-tiles first
  const int h  = blockIdx.z;
  const int q0 = qt * 128;
  const int kv_begin = blockIdx.x * STRIP_KV;
  const int kv_end   = q0 + 128;
  if (kv_begin >= kv_end) return;                   // strip above diagonal
  const int kv_stop = (kv_begin + STRIP_KV < kv_end) ? kv_begin + STRIP_KV : kv_end;

  __shared__ u16t lK[64 * KSTR];        // [kv][d]
  __shared__ u16t lVt[64 * VSTR];       // [d][kv^swz]
  __shared__ u16t lP[4 * 32 * PSTR];    // per-wave P scratch [q][kv^swz]

  const int t = threadIdx.x;
  const int lane = t & 63;
  const int wid  = t >> 6;
  const int quad = lane >> 4, l16 = lane & 15;
  const int wrow0 = q0 + wid * 32;

  // staging geometry
  const int krow = t >> 3, kcol = (t & 7) * 8;      // K: 2 chunks of 16B/thread
  const int vk0 = 4 * (t >> 4);                      // V: kv base (0..60)
  const int vd0 = 4 * (t & 15);                      // V: d base  (0..60)
  const int vswz = (t & 3) << 3;                     // V column swizzle key
  const u16t* Kbase = qkv + CDIM + h * HD;
  const u16t* Vbase = qkv + 2 * CDIM + h * HD;

  // Q fragments (A-operand layout), resident
  bf16x8 qf[2][2];
#pragma unroll
  for (int mt = 0; mt < 2; ++mt) {
    const int row = wrow0 + mt * 16 + l16;
#pragma unroll
    for (int kd = 0; kd < 2; ++kd)
      qf[mt][kd] = *(const bf16x8*)(qkv + (size_t)row * C3 + h * HD + kd * 32 + quad * 8);
  }

  f32x4 oacc[2][4], lacc[2];
#pragma unroll
  for (int qn = 0; qn < 2; ++qn) {
#pragma unroll
    for (int dn = 0; dn < 4; ++dn) oacc[qn][dn] = (f32x4){0.f, 0.f, 0.f, 0.f};
    lacc[qn] = (f32x4){0.f, 0.f, 0.f, 0.f};
  }
  bf16x8 ones;
#pragma unroll
  for (int i = 0; i < 8; ++i) ones[i] = (short)0x3F80;   // bf16 1.0

  u16t* lPw = &lP[wid * 32 * PSTR];
  const float SC = 0.125f * 1.4426950408889634f;   // 1/sqrt(D) * log2(e)
  const int pswz = ((l16 >> 2) & 3) << 3;          // P/V read-side swizzle key

  // prefetch registers
  uint4 kreg0, kreg1;
  union { uint2 u; u16t hw[4]; } vreg[4];

#define LOAD_TILE(KV0)                                                        \
  do {                                                                        \
    kreg0 = *(const uint4*)(Kbase + (size_t)((KV0) + krow) * C3 + kcol);      \
    kreg1 = *(const uint4*)(Kbase + (size_t)((KV0) + krow + 32) * C3 + kcol); \
    _Pragma("unroll")                                                         \
    for (int i = 0; i < 4; ++i)                                               \
      vreg[i].u = *(const uint2*)(Vbase + (size_t)((KV0) + vk0 + i) * C3 + vd0); \
  } while (0)

#define STORE_TILE()                                                          \
  do {                                                                        \
    *(uint4*)&lK[krow * KSTR + kcol] = kreg0;                                 \
    *(uint4*)&lK[(krow + 32) * KSTR + kcol] = kreg1;                          \
    _Pragma("unroll")                                                         \
    for (int j = 0; j < 4; ++j) {                                             \
      union { uint2 u; u16t hw[4]; } w;                                       \
      w.hw[0] = vreg[0].hw[j]; w.hw[1] = vreg[1].hw[j];                       \
      w.hw[2] = vreg[2].hw[j]; w.hw[3] = vreg[3].hw[j];                       \
      *(uint2*)&lVt[(vd0 + j) * VSTR + (vk0 ^ vswz)] = w.u;                   \
    }                                                                         \
  } while (0)

  LOAD_TILE(kv_begin);
  STORE_TILE();

  for (int kv0 = kv_begin; kv0 < kv_stop; kv0 += 64) {
    const bool havenext = (kv0 + 64 < kv_stop);
    if (havenext) LOAD_TILE(kv0 + 64);   // async: vmcnt wait lands after compute
    __syncthreads();                     // LDS tile kv0 visible to all waves

    if (kv0 <= wrow0 + 31) {             // wave-uniform skip of masked tiles
      // ---- S = Q K^T ----
      f32x4 sacc[2][4];
#pragma unroll
      for (int mt = 0; mt < 2; ++mt)
#pragma unroll
        for (int nt = 0; nt < 4; ++nt) sacc[mt][nt] = (f32x4){0.f, 0.f, 0.f, 0.f};
#pragma unroll
      for (int nt = 0; nt < 4; ++nt) {
        bf16x8 kf0 = *(const bf16x8*)&lK[(nt * 16 + l16) * KSTR + quad * 8];
        bf16x8 kf1 = *(const bf16x8*)&lK[(nt * 16 + l16) * KSTR + 32 + quad * 8];
#pragma unroll
        for (int mt = 0; mt < 2; ++mt) {
          sacc[mt][nt] = __builtin_amdgcn_mfma_f32_16x16x32_bf16(qf[mt][0], kf0, sacc[mt][nt], 0, 0, 0);
          sacc[mt][nt] = __builtin_amdgcn_mfma_f32_16x16x32_bf16(qf[mt][1], kf1, sacc[mt][nt], 0, 0, 0);
        }
      }
      const bool need_mask = (kv0 + 63 > wrow0);
      // ---- P = exp2(S*SC); write to per-wave LDS (quad-swizzled cols) ----
#pragma unroll
      for (int mt = 0; mt < 2; ++mt)
#pragma unroll
        for (int r = 0; r < 4; ++r) {
          const int row = wrow0 + mt * 16 + quad * 4 + r;
          u16t* prow = &lPw[(mt * 16 + quad * 4 + r) * PSTR];
#pragma unroll
          for (int nt = 0; nt < 4; ++nt) {
            float pv = __builtin_amdgcn_exp2f(sacc[mt][nt][r] * SC);
            if (need_mask && (kv0 + nt * 16 + l16 > row)) pv = 0.f;
            prow[(nt * 16 + l16) ^ (quad << 3)] = f2bf(pv);
          }
        }
      // Drain LDS writes before same-wave readback.
      __asm__ __volatile__("s_waitcnt lgkmcnt(0)" ::: "memory");
      // ---- O += P V ; l += P * ones ----
#pragma unroll
      for (int kk = 0; kk < 2; ++kk) {
        const int colb = (kk * 32 + quad * 8) ^ pswz;
        bf16x8 pf[2];
#pragma unroll
        for (int qn = 0; qn < 2; ++qn)
          pf[qn] = *(const bf16x8*)&lPw[(qn * 16 + l16) * PSTR + colb];
#pragma unroll
        for (int qn = 0; qn < 2; ++qn)
          lacc[qn] = __builtin_amdgcn_mfma_f32_16x16x32_bf16(pf[qn], ones, lacc[qn], 0, 0, 0);
#pragma unroll
        for (int dn = 0; dn < 4; ++dn) {
          bf16x8 vf = *(const bf16x8*)&lVt[(dn * 16 + l16) * VSTR + colb];
#pragma unroll
          for (int qn = 0; qn < 2; ++qn)
            oacc[qn][dn] = __builtin_amdgcn_mfma_f32_16x16x32_bf16(pf[qn], vf, oacc[qn][dn], 0, 0, 0);
        }
      }
    }
    __syncthreads();                     // all reads of LDS tile kv0 done
    if (havenext) STORE_TILE();          // overwrite with tile kv0+64
  }

  // ---- epilogue: line-contiguous fp32 atomics ----
  if (kv_begin <= wrow0 + 31) {
#pragma unroll
    for (int qn = 0; qn < 2; ++qn) {
#pragma unroll
      for (int r = 0; r < 4; ++r) {
        const int q = wrow0 + qn * 16 + quad * 4 + r;
        float* baseq = accO + ((size_t)h * T_SEQ + q) * HD;
#pragma unroll
        for (int dn = 0; dn < 4; ++dn)
          atomicAdd(baseq + dn * 16 + l16, oacc[qn][dn][r]);
        if (l16 == 0)
          atomicAdd(accL + (size_t)h * T_SEQ + q, lacc[qn][r]);
      }
    }
  }
#undef LOAD_TILE
#undef STORE_TILE
}

__global__ __launch_bounds__(256) void zero_f32x4(float* __restrict__ p, int n4) {
  int i = blockIdx.x * 256 + threadIdx.x;
  const int stride = gridDim.x * 256;
  f32x4 z = (f32x4){0.f, 0.f, 0.f, 0.f};
  for (; i < n4; i += stride) ((f32x4*)p)[i] = z;
}

__global__ __launch_bounds__(256) void attn_normalize(const float* __restrict__ accO,
                                                      const float* __restrict__ accL,
                                                      u16t* __restrict__ y) {
  const int i = blockIdx.x * 256 + threadIdx.x;   // over T*C
  const int q = i / CDIM, c = i % CDIM;
  const int h = c >> 6, d = c & 63;
  const float o = accO[((size_t)h * T_SEQ + q) * HD + d];
  const float l = accL[(size_t)h * T_SEQ + q];
  y[i] = f2bf(o / l);
}

// ---------------------------------------------------------------------------
extern "C" void kernel_launch(void* const* d_in, const int* in_sizes, int n_in,
                              void* d_out, int out_size, void* d_ws, size_t ws_size,
                              hipStream_t stream) {
  const void* x     = d_in[0];
  // d_in[1] = mask (unused — causal mask applied analytically)
  const void* Wqkv  = d_in[2];
  const void* bqkv  = d_in[3];
  const void* Wproj = d_in[4];
  const void* bproj = d_in[5];

  u16t* qkv    = (u16t*)d_ws;                     // [4096][2304] bf16
  u16t* ybuf   = qkv    + (size_t)T_SEQ * C3;     // [4096][768]  bf16
  u16t* WqkvT  = ybuf   + (size_t)T_SEQ * CDIM;   // [2304][768]  bf16
  u16t* WprojT = WqkvT  + (size_t)C3 * CDIM;      // [768][768]   bf16
  u16t* xb     = WprojT + (size_t)CDIM * CDIM;    // [4096][768]  bf16
  float* accO  = (float*)(xb + (size_t)T_SEQ * CDIM);  // [12][4096][64] f32
  float* accL  = accO + (size_t)NH * T_SEQ * HD;       // [12][4096]     f32
  int*  flag   = (int*)(accL + (size_t)NH * T_SEQ);

  detect_dtype<<<1, 256, 0, stream>>>((const u16t*)x, flag);
  convert_to_bf16<<<1024, 256, 0, stream>>>(x, xb, T_SEQ * CDIM, flag);
  transpose_to_bf16<<<dim3(C3 / 32, CDIM / 32), dim3(32, 8), 0, stream>>>(
      Wqkv, WqkvT, CDIM, C3, flag);
  transpose_to_bf16<<<dim3(CDIM / 32, CDIM / 32), dim3(32, 8), 0, stream>>>(
      Wproj, WprojT, CDIM, CDIM, flag);
  gemm_bt_bias<<<dim3(C3 / 128, T_SEQ / 128), 256, 0, stream>>>(
      xb, WqkvT, bqkv, qkv, T_SEQ, C3, CDIM, flag, 0);
  zero_f32x4<<<512, 256, 0, stream>>>(accO, (int)((size_t)NH * T_SEQ * (HD + 1) / 4));
  attn_partial<<<dim3(T_SEQ / STRIP_KV, T_SEQ / 128, NH), 256, 0, stream>>>(
      qkv, accO, accL);
  attn_normalize<<<(T_SEQ * CDIM) / 256, 256, 0, stream>>>(accO, accL, ybuf);
  gemm_bt_bias<<<dim3(CDIM / 128, T_SEQ / 128), 256, 0, stream>>>(
      ybuf, WprojT, bproj, d_out, T_SEQ, CDIM, CDIM, flag, 1);
}

// Round 6
// 308.801 us; speedup vs baseline: 1.0029x; 1.0029x over previous
//
#include <hip/hip_runtime.h>

typedef unsigned short u16t;
typedef short bf16x8 __attribute__((ext_vector_type(8)));
typedef float f32x4 __attribute__((ext_vector_type(4)));

#define T_SEQ 4096
#define NH    12
#define HD    64
#define C3    2304
#define CDIM  768
#define STRIP_KV 512

__device__ __forceinline__ float bf2f(u16t u) {
  union { unsigned int i; float f; } c; c.i = ((unsigned int)u) << 16; return c.f;
}
__device__ __forceinline__ u16t f2bf(float f) {
  union { float f; unsigned int i; } c; c.f = f;
  unsigned int u = c.i;
  u += 0x7fffu + ((u >> 16) & 1u);   // RNE
  return (u16t)(u >> 16);
}
__device__ __forceinline__ void gload16(const u16t* g, u16t* l) {
  __builtin_amdgcn_global_load_lds((const __attribute__((address_space(1))) void*)g,
                                   (__attribute__((address_space(3))) void*)l,
                                   16, 0, 0);
}

// Barrier that drains ONLY the LDS/DS counter — in-flight global->VGPR
// prefetch loads stay outstanding across the barrier (unlike __syncthreads,
// which emits s_waitcnt vmcnt(0) and kills software pipelining).  Safe here:
// the only cross-wave shared state is LDS, covered by lgkmcnt(0)+s_barrier;
// VGPR prefetch data is wave-private (compiler auto-waits vmcnt on use).
#define BARRIER_LGKM() __asm__ __volatile__("s_waitcnt lgkmcnt(0)\n\ts_barrier" ::: "memory")

// ---------------------------------------------------------------------------
// Input-dtype detector (1 = fp32 inputs, 0 = bf16 inputs).
// ---------------------------------------------------------------------------
__global__ void detect_dtype(const u16t* __restrict__ x, int* __restrict__ flag) {
  __shared__ int cnt[256];
  int c = 0;
  for (int i = threadIdx.x; i < 4096; i += 256) {
    unsigned e = (x[2 * i] >> 7) & 0xFFu;
    c += (e < 112u || e > 136u) ? 1 : 0;
  }
  cnt[threadIdx.x] = c;
  __syncthreads();
  if (threadIdx.x == 0) {
    int s = 0;
    for (int i = 0; i < 256; ++i) s += cnt[i];
    *flag = (s > 2048) ? 1 : 0;
  }
}

__global__ __launch_bounds__(256) void convert_to_bf16(const void* __restrict__ in,
                                                       u16t* __restrict__ out, int n,
                                                       const int* __restrict__ flag) {
  const bool f32 = (*flag != 0);
  int i = blockIdx.x * 256 + threadIdx.x;
  const int stride = gridDim.x * 256;
  if (f32) {
    const float* p = (const float*)in;
    for (; i < n; i += stride) out[i] = f2bf(p[i]);
  } else {
    const u16t* p = (const u16t*)in;
    for (; i < n; i += stride) out[i] = p[i];
  }
}

__global__ __launch_bounds__(256) void transpose_to_bf16(const void* __restrict__ in,
                                                         u16t* __restrict__ out,
                                                         int R, int Cc,
                                                         const int* __restrict__ flag) {
  __shared__ u16t tile[32][33];
  const bool f32 = (*flag != 0);
  const int tx = threadIdx.x, ty = threadIdx.y;       // block (32,8)
  const int c0 = blockIdx.x * 32, r0 = blockIdx.y * 32;
#pragma unroll
  for (int i = 0; i < 32; i += 8) {
    const size_t idx = (size_t)(r0 + ty + i) * Cc + c0 + tx;
    tile[ty + i][tx] = f32 ? f2bf(((const float*)in)[idx]) : ((const u16t*)in)[idx];
  }
  __syncthreads();
#pragma unroll
  for (int i = 0; i < 32; i += 8)
    out[(size_t)(c0 + ty + i) * R + r0 + tx] = tile[tx][ty + i];
}

// ---------------------------------------------------------------------------
// C[M,N] = A[M,K]*B[K,N] + bias[N]; Bt row-major [N][K]; 128x128 tile, BK=32.
// (global_load_lds staging: the full __syncthreads drain is semantically
//  required here — consumers read LDS produced by other waves' VMEM ops.)
// ---------------------------------------------------------------------------
__global__ __launch_bounds__(256) void gemm_bt_bias(
    const u16t* __restrict__ A, const u16t* __restrict__ Bt,
    const void* __restrict__ bias, void* __restrict__ Cout,
    int M, int N, int K, const int* __restrict__ flag, int follow_flag) {
  __shared__ u16t lA[128 * 32];
  __shared__ u16t lB[128 * 32];
  const bool f32io = (*flag != 0);
  const int t = threadIdx.x;
  const int lane = t & 63;
  const int wid  = t >> 6;
  const int quad = lane >> 4, l16 = lane & 15;
  const int m0 = blockIdx.y * 128, n0 = blockIdx.x * 128;
  const int wm = (wid >> 1) * 64, wn = (wid & 1) * 64;

  f32x4 acc[4][4];
#pragma unroll
  for (int i = 0; i < 4; ++i)
#pragma unroll
    for (int j = 0; j < 4; ++j) acc[i][j] = (f32x4){0.f, 0.f, 0.f, 0.f};

  for (int k0 = 0; k0 < K; k0 += 32) {
    {
      int e = t;
      gload16(A  + (size_t)(m0 + (e >> 2)) * K + k0 + (e & 3) * 8, &lA[e * 8]);
      gload16(Bt + (size_t)(n0 + (e >> 2)) * K + k0 + (e & 3) * 8, &lB[e * 8]);
      e = 256 + t;
      gload16(A  + (size_t)(m0 + (e >> 2)) * K + k0 + (e & 3) * 8, &lA[e * 8]);
      gload16(Bt + (size_t)(n0 + (e >> 2)) * K + k0 + (e & 3) * 8, &lB[e * 8]);
    }
    __syncthreads();
    bf16x8 af[4], bfr[4];
#pragma unroll
    for (int i = 0; i < 4; ++i)
      af[i] = *(const bf16x8*)&lA[(wm + i * 16 + l16) * 32 + quad * 8];
#pragma unroll
    for (int i = 0; i < 4; ++i)
      bfr[i] = *(const bf16x8*)&lB[(wn + i * 16 + l16) * 32 + quad * 8];
#pragma unroll
    for (int i = 0; i < 4; ++i)
#pragma unroll
      for (int j = 0; j < 4; ++j)
        acc[i][j] = __builtin_amdgcn_mfma_f32_16x16x32_bf16(af[i], bfr[j], acc[i][j], 0, 0, 0);
    __syncthreads();
  }

  const bool out_f32 = (follow_flag != 0) && f32io;
#pragma unroll
  for (int j = 0; j < 4; ++j) {
    const int col = n0 + wn + j * 16 + l16;
    const float bv = f32io ? ((const float*)bias)[col] : bf2f(((const u16t*)bias)[col]);
#pragma unroll
    for (int i = 0; i < 4; ++i) {
      const int rowb = m0 + wm + i * 16 + quad * 4;
#pragma unroll
      for (int r = 0; r < 4; ++r) {
        const float val = acc[i][j][r] + bv;
        const size_t idx = (size_t)(rowb + r) * N + col;
        if (out_f32) ((float*)Cout)[idx] = val;
        else         ((u16t*)Cout)[idx] = f2bf(val);
      }
    }
  }
}

// ---------------------------------------------------------------------------
// Split-KV causal attention, UNNORMALIZED exp2 softmax, register-carried
// prefetch pipeline with LGKM-only barriers (global prefetch loads for tile
// i+1 remain in flight across the entire compute of tile i).
// One block = one 512-wide KV strip of one 128-row Q tile of one head;
// grid (8,32,12), heavy q-tiles first.  LDS 40960 B -> 4 blocks/CU.
// ---------------------------------------------------------------------------
#define KSTR 80
#define VSTR 80
#define PSTR 80

__global__ __launch_bounds__(256, 4) void attn_partial(const u16t* __restrict__ qkv,
                                                       float* __restrict__ accO,
                                                       float* __restrict__ accL) {
  const int qt = 31 - (int)blockIdx.y;              // heavy q-tiles first
  const int h  = blockIdx.z;
  const int q0 = qt * 128;
  const int kv_begin = blockIdx.x * STRIP_KV;
  const int kv_end   = q0 + 128;
  if (kv_begin >= kv_end) return;                   // strip above diagonal
  const int kv_stop = (kv_begin + STRIP_KV < kv_end) ? kv_begin + STRIP_KV : kv_end;

  __shared__ u16t lK[64 * KSTR];        // [kv][d]
  __shared__ u16t lVt[64 * VSTR];       // [d][kv^swz]
  __shared__ u16t lP[4 * 32 * PSTR];    // per-wave P scratch [q][kv^swz]

  const int t = threadIdx.x;
  const int lane = t & 63;
  const int wid  = t >> 6;
  const int quad = lane >> 4, l16 = lane & 15;
  const int wrow0 = q0 + wid * 32;

  // staging geometry
  const int krow = t >> 3, kcol = (t & 7) * 8;      // K: 2 chunks of 16B/thread
  const int vk0 = 4 * (t >> 4);                      // V: kv base (0..60)
  const int vd0 = 4 * (t & 15);                      // V: d base  (0..60)
  const int vswz = (t & 3) << 3;                     // V column swizzle key
  const u16t* Kbase = qkv + CDIM + h * HD;
  const u16t* Vbase = qkv + 2 * CDIM + h * HD;

  // Q fragments (A-operand layout), resident
  bf16x8 qf[2][2];
#pragma unroll
  for (int mt = 0; mt < 2; ++mt) {
    const int row = wrow0 + mt * 16 + l16;
#pragma unroll
    for (int kd = 0; kd < 2; ++kd)
      qf[mt][kd] = *(const bf16x8*)(qkv + (size_t)row * C3 + h * HD + kd * 32 + quad * 8);
  }

  f32x4 oacc[2][4], lacc[2];
#pragma unroll
  for (int qn = 0; qn < 2; ++qn) {
#pragma unroll
    for (int dn = 0; dn < 4; ++dn) oacc[qn][dn] = (f32x4){0.f, 0.f, 0.f, 0.f};
    lacc[qn] = (f32x4){0.f, 0.f, 0.f, 0.f};
  }
  bf16x8 ones;
#pragma unroll
  for (int i = 0; i < 8; ++i) ones[i] = (short)0x3F80;   // bf16 1.0

  u16t* lPw = &lP[wid * 32 * PSTR];
  const float SC = 0.125f * 1.4426950408889634f;   // 1/sqrt(D) * log2(e)
  const int pswz = ((l16 >> 2) & 3) << 3;          // P/V read-side swizzle key

  // prefetch registers
  uint4 kreg0, kreg1;
  union { uint2 u; u16t hw[4]; } vreg[4];

#define LOAD_TILE(KV0)                                                        \
  do {                                                                        \
    kreg0 = *(const uint4*)(Kbase + (size_t)((KV0) + krow) * C3 + kcol);      \
    kreg1 = *(const uint4*)(Kbase + (size_t)((KV0) + krow + 32) * C3 + kcol); \
    _Pragma("unroll")                                                         \
    for (int i = 0; i < 4; ++i)                                               \
      vreg[i].u = *(const uint2*)(Vbase + (size_t)((KV0) + vk0 + i) * C3 + vd0); \
  } while (0)

#define STORE_TILE()                                                          \
  do {                                                                        \
    *(uint4*)&lK[krow * KSTR + kcol] = kreg0;                                 \
    *(uint4*)&lK[(krow + 32) * KSTR + kcol] = kreg1;                          \
    _Pragma("unroll")                                                         \
    for (int j = 0; j < 4; ++j) {                                             \
      union { uint2 u; u16t hw[4]; } w;                                       \
      w.hw[0] = vreg[0].hw[j]; w.hw[1] = vreg[1].hw[j];                       \
      w.hw[2] = vreg[2].hw[j]; w.hw[3] = vreg[3].hw[j];                       \
      *(uint2*)&lVt[(vd0 + j) * VSTR + (vk0 ^ vswz)] = w.u;                   \
    }                                                                         \
  } while (0)

  LOAD_TILE(kv_begin);
  STORE_TILE();

  for (int kv0 = kv_begin; kv0 < kv_stop; kv0 += 64) {
    const bool havenext = (kv0 + 64 < kv_stop);
    if (havenext) LOAD_TILE(kv0 + 64);   // stays in flight across compute
    BARRIER_LGKM();                      // LDS tile kv0 visible to all waves

    if (kv0 <= wrow0 + 31) {             // wave-uniform skip of masked tiles
      // ---- S = Q K^T ----
      f32x4 sacc[2][4];
#pragma unroll
      for (int mt = 0; mt < 2; ++mt)
#pragma unroll
        for (int nt = 0; nt < 4; ++nt) sacc[mt][nt] = (f32x4){0.f, 0.f, 0.f, 0.f};
#pragma unroll
      for (int nt = 0; nt < 4; ++nt) {
        bf16x8 kf0 = *(const bf16x8*)&lK[(nt * 16 + l16) * KSTR + quad * 8];
        bf16x8 kf1 = *(const bf16x8*)&lK[(nt * 16 + l16) * KSTR + 32 + quad * 8];
#pragma unroll
        for (int mt = 0; mt < 2; ++mt) {
          sacc[mt][nt] = __builtin_amdgcn_mfma_f32_16x16x32_bf16(qf[mt][0], kf0, sacc[mt][nt], 0, 0, 0);
          sacc[mt][nt] = __builtin_amdgcn_mfma_f32_16x16x32_bf16(qf[mt][1], kf1, sacc[mt][nt], 0, 0, 0);
        }
      }
      const bool need_mask = (kv0 + 63 > wrow0);
      // ---- P = exp2(S*SC); write to per-wave LDS (quad-swizzled cols) ----
#pragma unroll
      for (int mt = 0; mt < 2; ++mt)
#pragma unroll
        for (int r = 0; r < 4; ++r) {
          const int row = wrow0 + mt * 16 + quad * 4 + r;
          u16t* prow = &lPw[(mt * 16 + quad * 4 + r) * PSTR];
#pragma unroll
          for (int nt = 0; nt < 4; ++nt) {
            float pv = __builtin_amdgcn_exp2f(sacc[mt][nt][r] * SC);
            if (need_mask && (kv0 + nt * 16 + l16 > row)) pv = 0.f;
            prow[(nt * 16 + l16) ^ (quad << 3)] = f2bf(pv);
          }
        }
      // Drain LDS writes before same-wave readback (intra-wave RAW).
      __asm__ __volatile__("s_waitcnt lgkmcnt(0)" ::: "memory");
      // ---- O += P V ; l += P * ones ----
#pragma unroll
      for (int kk = 0; kk < 2; ++kk) {
        const int colb = (kk * 32 + quad * 8) ^ pswz;
        bf16x8 pf[2];
#pragma unroll
        for (int qn = 0; qn < 2; ++qn)
          pf[qn] = *(const bf16x8*)&lPw[(qn * 16 + l16) * PSTR + colb];
#pragma unroll
        for (int qn = 0; qn < 2; ++qn)
          lacc[qn] = __builtin_amdgcn_mfma_f32_16x16x32_bf16(pf[qn], ones, lacc[qn], 0, 0, 0);
#pragma unroll
        for (int dn = 0; dn < 4; ++dn) {
          bf16x8 vf = *(const bf16x8*)&lVt[(dn * 16 + l16) * VSTR + colb];
#pragma unroll
          for (int qn = 0; qn < 2; ++qn)
            oacc[qn][dn] = __builtin_amdgcn_mfma_f32_16x16x32_bf16(pf[qn], vf, oacc[qn][dn], 0, 0, 0);
        }
      }
    }
    BARRIER_LGKM();                      // all reads of LDS tile kv0 done
    if (havenext) STORE_TILE();          // overwrite with tile kv0+64
  }

  // ---- epilogue: line-contiguous fp32 atomics ----
  if (kv_begin <= wrow0 + 31) {
#pragma unroll
    for (int qn = 0; qn < 2; ++qn) {
#pragma unroll
      for (int r = 0; r < 4; ++r) {
        const int q = wrow0 + qn * 16 + quad * 4 + r;
        float* baseq = accO + ((size_t)h * T_SEQ + q) * HD;
#pragma unroll
        for (int dn = 0; dn < 4; ++dn)
          atomicAdd(baseq + dn * 16 + l16, oacc[qn][dn][r]);
        if (l16 == 0)
          atomicAdd(accL + (size_t)h * T_SEQ + q, lacc[qn][r]);
      }
    }
  }
#undef LOAD_TILE
#undef STORE_TILE
}

__global__ __launch_bounds__(256) void zero_f32x4(float* __restrict__ p, int n4) {
  int i = blockIdx.x * 256 + threadIdx.x;
  const int stride = gridDim.x * 256;
  f32x4 z = (f32x4){0.f, 0.f, 0.f, 0.f};
  for (; i < n4; i += stride) ((f32x4*)p)[i] = z;
}

__global__ __launch_bounds__(256) void attn_normalize(const float* __restrict__ accO,
                                                      const float* __restrict__ accL,
                                                      u16t* __restrict__ y) {
  const int i = blockIdx.x * 256 + threadIdx.x;   // over T*C
  const int q = i / CDIM, c = i % CDIM;
  const int h = c >> 6, d = c & 63;
  const float o = accO[((size_t)h * T_SEQ + q) * HD + d];
  const float l = accL[(size_t)h * T_SEQ + q];
  y[i] = f2bf(o / l);
}

// ---------------------------------------------------------------------------
extern "C" void kernel_launch(void* const* d_in, const int* in_sizes, int n_in,
                              void* d_out, int out_size, void* d_ws, size_t ws_size,
                              hipStream_t stream) {
  const void* x     = d_in[0];
  // d_in[1] = mask (unused — causal mask applied analytically)
  const void* Wqkv  = d_in[2];
  const void* bqkv  = d_in[3];
  const void* Wproj = d_in[4];
  const void* bproj = d_in[5];

  u16t* qkv    = (u16t*)d_ws;                     // [4096][2304] bf16
  u16t* ybuf   = qkv    + (size_t)T_SEQ * C3;     // [4096][768]  bf16
  u16t* WqkvT  = ybuf   + (size_t)T_SEQ * CDIM;   // [2304][768]  bf16
  u16t* WprojT = WqkvT  + (size_t)C3 * CDIM;      // [768][768]   bf16
  u16t* xb     = WprojT + (size_t)CDIM * CDIM;    // [4096][768]  bf16
  float* accO  = (float*)(xb + (size_t)T_SEQ * CDIM);  // [12][4096][64] f32
  float* accL  = accO + (size_t)NH * T_SEQ * HD;       // [12][4096]     f32
  int*  flag   = (int*)(accL + (size_t)NH * T_SEQ);

  detect_dtype<<<1, 256, 0, stream>>>((const u16t*)x, flag);
  convert_to_bf16<<<1024, 256, 0, stream>>>(x, xb, T_SEQ * CDIM, flag);
  transpose_to_bf16<<<dim3(C3 / 32, CDIM / 32), dim3(32, 8), 0, stream>>>(
      Wqkv, WqkvT, CDIM, C3, flag);
  transpose_to_bf16<<<dim3(CDIM / 32, CDIM / 32), dim3(32, 8), 0, stream>>>(
      Wproj, WprojT, CDIM, CDIM, flag);
  gemm_bt_bias<<<dim3(C3 / 128, T_SEQ / 128), 256, 0, stream>>>(
      xb, WqkvT, bqkv, qkv, T_SEQ, C3, CDIM, flag, 0);
  zero_f32x4<<<512, 256, 0, stream>>>(accO, (int)((size_t)NH * T_SEQ * (HD + 1) / 4));
  attn_partial<<<dim3(T_SEQ / STRIP_KV, T_SEQ / 128, NH), 256, 0, stream>>>(
      qkv, accO, accL);
  attn_normalize<<<(T_SEQ * CDIM) / 256, 256, 0, stream>>>(accO, accL, ybuf);
  gemm_bt_bias<<<dim3(CDIM / 128, T_SEQ / 128), 256, 0, stream>>>(
      ybuf, WprojT, bproj, d_out, T_SEQ, CDIM, CDIM, flag, 1);
}

// Round 7
// 302.507 us; speedup vs baseline: 1.0237x; 1.0208x over previous
//
#include <hip/hip_runtime.h>

typedef unsigned short u16t;
typedef short bf16x8 __attribute__((ext_vector_type(8)));
typedef float f32x4 __attribute__((ext_vector_type(4)));

#define T_SEQ 4096
#define NH    12
#define HD    64
#define C3    2304
#define CDIM  768
#define STRIP_KV 1024
#define SLOTS 80          // sum over qt of ceil((qt+1)/8)

__device__ __forceinline__ float bf2f(u16t u) {
  union { unsigned int i; float f; } c; c.i = ((unsigned int)u) << 16; return c.f;
}
__device__ __forceinline__ u16t f2bf(float f) {
  union { float f; unsigned int i; } c; c.f = f;
  unsigned int u = c.i;
  u += 0x7fffu + ((u >> 16) & 1u);   // RNE
  return (u16t)(u >> 16);
}
__device__ __forceinline__ void gload16(const u16t* g, u16t* l) {
  __builtin_amdgcn_global_load_lds((const __attribute__((address_space(1))) void*)g,
                                   (__attribute__((address_space(3))) void*)l,
                                   16, 0, 0);
}

// LDS-only barrier: in-flight global->VGPR prefetch stays outstanding.
#define BARRIER_LGKM() __asm__ __volatile__("s_waitcnt lgkmcnt(0)\n\ts_barrier" ::: "memory")

// ---------------------------------------------------------------------------
__global__ void detect_dtype(const u16t* __restrict__ x, int* __restrict__ flag) {
  __shared__ int cnt[256];
  int c = 0;
  for (int i = threadIdx.x; i < 4096; i += 256) {
    unsigned e = (x[2 * i] >> 7) & 0xFFu;
    c += (e < 112u || e > 136u) ? 1 : 0;
  }
  cnt[threadIdx.x] = c;
  __syncthreads();
  if (threadIdx.x == 0) {
    int s = 0;
    for (int i = 0; i < 256; ++i) s += cnt[i];
    *flag = (s > 2048) ? 1 : 0;
  }
}

__global__ __launch_bounds__(256) void convert_to_bf16(const void* __restrict__ in,
                                                       u16t* __restrict__ out, int n,
                                                       const int* __restrict__ flag) {
  const bool f32 = (*flag != 0);
  int i = blockIdx.x * 256 + threadIdx.x;
  const int stride = gridDim.x * 256;
  if (f32) {
    const float* p = (const float*)in;
    for (; i < n; i += stride) out[i] = f2bf(p[i]);
  } else {
    const u16t* p = (const u16t*)in;
    for (; i < n; i += stride) out[i] = p[i];
  }
}

__global__ __launch_bounds__(256) void transpose_to_bf16(const void* __restrict__ in,
                                                         u16t* __restrict__ out,
                                                         int R, int Cc,
                                                         const int* __restrict__ flag) {
  __shared__ u16t tile[32][33];
  const bool f32 = (*flag != 0);
  const int tx = threadIdx.x, ty = threadIdx.y;       // block (32,8)
  const int c0 = blockIdx.x * 32, r0 = blockIdx.y * 32;
#pragma unroll
  for (int i = 0; i < 32; i += 8) {
    const size_t idx = (size_t)(r0 + ty + i) * Cc + c0 + tx;
    tile[ty + i][tx] = f32 ? f2bf(((const float*)in)[idx]) : ((const u16t*)in)[idx];
  }
  __syncthreads();
#pragma unroll
  for (int i = 0; i < 32; i += 8)
    out[(size_t)(c0 + ty + i) * R + r0 + tx] = tile[tx][ty + i];
}

// ---------------------------------------------------------------------------
// C[M,N] = A[M,K]*B[K,N] + bias[N]; Bt row-major [N][K]; 128x128 tile, BK=32.
// ---------------------------------------------------------------------------
__global__ __launch_bounds__(256) void gemm_bt_bias(
    const u16t* __restrict__ A, const u16t* __restrict__ Bt,
    const void* __restrict__ bias, void* __restrict__ Cout,
    int M, int N, int K, const int* __restrict__ flag, int follow_flag) {
  __shared__ u16t lA[128 * 32];
  __shared__ u16t lB[128 * 32];
  const bool f32io = (*flag != 0);
  const int t = threadIdx.x;
  const int lane = t & 63;
  const int wid  = t >> 6;
  const int quad = lane >> 4, l16 = lane & 15;
  const int m0 = blockIdx.y * 128, n0 = blockIdx.x * 128;
  const int wm = (wid >> 1) * 64, wn = (wid & 1) * 64;

  f32x4 acc[4][4];
#pragma unroll
  for (int i = 0; i < 4; ++i)
#pragma unroll
    for (int j = 0; j < 4; ++j) acc[i][j] = (f32x4){0.f, 0.f, 0.f, 0.f};

  for (int k0 = 0; k0 < K; k0 += 32) {
    {
      int e = t;
      gload16(A  + (size_t)(m0 + (e >> 2)) * K + k0 + (e & 3) * 8, &lA[e * 8]);
      gload16(Bt + (size_t)(n0 + (e >> 2)) * K + k0 + (e & 3) * 8, &lB[e * 8]);
      e = 256 + t;
      gload16(A  + (size_t)(m0 + (e >> 2)) * K + k0 + (e & 3) * 8, &lA[e * 8]);
      gload16(Bt + (size_t)(n0 + (e >> 2)) * K + k0 + (e & 3) * 8, &lB[e * 8]);
    }
    __syncthreads();
    bf16x8 af[4], bfr[4];
#pragma unroll
    for (int i = 0; i < 4; ++i)
      af[i] = *(const bf16x8*)&lA[(wm + i * 16 + l16) * 32 + quad * 8];
#pragma unroll
    for (int i = 0; i < 4; ++i)
      bfr[i] = *(const bf16x8*)&lB[(wn + i * 16 + l16) * 32 + quad * 8];
#pragma unroll
    for (int i = 0; i < 4; ++i)
#pragma unroll
      for (int j = 0; j < 4; ++j)
        acc[i][j] = __builtin_amdgcn_mfma_f32_16x16x32_bf16(af[i], bfr[j], acc[i][j], 0, 0, 0);
    __syncthreads();
  }

  const bool out_f32 = (follow_flag != 0) && f32io;
#pragma unroll
  for (int j = 0; j < 4; ++j) {
    const int col = n0 + wn + j * 16 + l16;
    const float bv = f32io ? ((const float*)bias)[col] : bf2f(((const u16t*)bias)[col]);
#pragma unroll
    for (int i = 0; i < 4; ++i) {
      const int rowb = m0 + wm + i * 16 + quad * 4;
#pragma unroll
      for (int r = 0; r < 4; ++r) {
        const float val = acc[i][j][r] + bv;
        const size_t idx = (size_t)(rowb + r) * N + col;
        if (out_f32) ((float*)Cout)[idx] = val;
        else         ((u16t*)Cout)[idx] = f2bf(val);
      }
    }
  }
}

// ---------------------------------------------------------------------------
// Split-KV causal attention, UNNORMALIZED exp2 softmax.  NO ATOMICS: each
// block writes partial O / l to a private compact slot (plain stores);
// attn_normalize sums the <=4 slots per row.  Strip = 1024 kv (<=16 tiles).
// slot(qt,s) = qt + 4g(g-1) + r*g + s  where g=qt>>3, r=qt&7  (80 slots/head).
// grid (4,32,12), heavy q-tiles first.  LDS 40960 B -> 4 blocks/CU.
// ---------------------------------------------------------------------------
#define KSTR 80
#define VSTR 80
#define PSTR 80

__global__ __launch_bounds__(256, 4) void attn_partial(const u16t* __restrict__ qkv,
                                                       float* __restrict__ pO,
                                                       float* __restrict__ pL) {
  const int qt = 31 - (int)blockIdx.y;              // heavy q-tiles first
  const int h  = blockIdx.z;
  const int q0 = qt * 128;
  const int kv_begin = blockIdx.x * STRIP_KV;
  const int kv_end   = q0 + 128;
  if (kv_begin >= kv_end) return;                   // strip above diagonal
  const int kv_stop = (kv_begin + STRIP_KV < kv_end) ? kv_begin + STRIP_KV : kv_end;
  const int g = qt >> 3, rr = qt & 7;
  const int slot = qt + 4 * g * (g - 1) + rr * g + (int)blockIdx.x;

  __shared__ u16t lK[64 * KSTR];        // [kv][d]
  __shared__ u16t lVt[64 * VSTR];       // [d][kv^swz]
  __shared__ u16t lP[4 * 32 * PSTR];    // per-wave P scratch [q][kv^swz]

  const int t = threadIdx.x;
  const int lane = t & 63;
  const int wid  = t >> 6;
  const int quad = lane >> 4, l16 = lane & 15;
  const int wrow0 = q0 + wid * 32;

  // staging geometry
  const int krow = t >> 3, kcol = (t & 7) * 8;      // K: 2 chunks of 16B/thread
  const int vk0 = 4 * (t >> 4);                      // V: kv base (0..60)
  const int vd0 = 4 * (t & 15);                      // V: d base  (0..60)
  const int vswz = (t & 3) << 3;                     // V column swizzle key
  const u16t* Kbase = qkv + CDIM + h * HD;
  const u16t* Vbase = qkv + 2 * CDIM + h * HD;

  // Q fragments (A-operand layout), resident
  bf16x8 qf[2][2];
#pragma unroll
  for (int mt = 0; mt < 2; ++mt) {
    const int row = wrow0 + mt * 16 + l16;
#pragma unroll
    for (int kd = 0; kd < 2; ++kd)
      qf[mt][kd] = *(const bf16x8*)(qkv + (size_t)row * C3 + h * HD + kd * 32 + quad * 8);
  }

  f32x4 oacc[2][4], lacc[2];
#pragma unroll
  for (int qn = 0; qn < 2; ++qn) {
#pragma unroll
    for (int dn = 0; dn < 4; ++dn) oacc[qn][dn] = (f32x4){0.f, 0.f, 0.f, 0.f};
    lacc[qn] = (f32x4){0.f, 0.f, 0.f, 0.f};
  }
  bf16x8 ones;
#pragma unroll
  for (int i = 0; i < 8; ++i) ones[i] = (short)0x3F80;   // bf16 1.0

  u16t* lPw = &lP[wid * 32 * PSTR];
  const float SC = 0.125f * 1.4426950408889634f;   // 1/sqrt(D) * log2(e)
  const int pswz = ((l16 >> 2) & 3) << 3;          // P/V read-side swizzle key

  // prefetch registers
  uint4 kreg0, kreg1;
  union { uint2 u; u16t hw[4]; } vreg[4];

#define LOAD_TILE(KV0)                                                        \
  do {                                                                        \
    kreg0 = *(const uint4*)(Kbase + (size_t)((KV0) + krow) * C3 + kcol);      \
    kreg1 = *(const uint4*)(Kbase + (size_t)((KV0) + krow + 32) * C3 + kcol); \
    _Pragma("unroll")                                                         \
    for (int i = 0; i < 4; ++i)                                               \
      vreg[i].u = *(const uint2*)(Vbase + (size_t)((KV0) + vk0 + i) * C3 + vd0); \
  } while (0)

#define STORE_TILE()                                                          \
  do {                                                                        \
    *(uint4*)&lK[krow * KSTR + kcol] = kreg0;                                 \
    *(uint4*)&lK[(krow + 32) * KSTR + kcol] = kreg1;                          \
    _Pragma("unroll")                                                         \
    for (int j = 0; j < 4; ++j) {                                             \
      union { uint2 u; u16t hw[4]; } w;                                       \
      w.hw[0] = vreg[0].hw[j]; w.hw[1] = vreg[1].hw[j];                       \
      w.hw[2] = vreg[2].hw[j]; w.hw[3] = vreg[3].hw[j];                       \
      *(uint2*)&lVt[(vd0 + j) * VSTR + (vk0 ^ vswz)] = w.u;                   \
    }                                                                         \
  } while (0)

  LOAD_TILE(kv_begin);
  STORE_TILE();

  for (int kv0 = kv_begin; kv0 < kv_stop; kv0 += 64) {
    const bool havenext = (kv0 + 64 < kv_stop);
    if (havenext) LOAD_TILE(kv0 + 64);   // stays in flight across compute
    BARRIER_LGKM();                      // LDS tile kv0 visible to all waves

    if (kv0 <= wrow0 + 31) {             // wave-uniform skip of masked tiles
      // ---- S = Q K^T ----
      f32x4 sacc[2][4];
#pragma unroll
      for (int mt = 0; mt < 2; ++mt)
#pragma unroll
        for (int nt = 0; nt < 4; ++nt) sacc[mt][nt] = (f32x4){0.f, 0.f, 0.f, 0.f};
#pragma unroll
      for (int nt = 0; nt < 4; ++nt) {
        bf16x8 kf0 = *(const bf16x8*)&lK[(nt * 16 + l16) * KSTR + quad * 8];
        bf16x8 kf1 = *(const bf16x8*)&lK[(nt * 16 + l16) * KSTR + 32 + quad * 8];
#pragma unroll
        for (int mt = 0; mt < 2; ++mt) {
          sacc[mt][nt] = __builtin_amdgcn_mfma_f32_16x16x32_bf16(qf[mt][0], kf0, sacc[mt][nt], 0, 0, 0);
          sacc[mt][nt] = __builtin_amdgcn_mfma_f32_16x16x32_bf16(qf[mt][1], kf1, sacc[mt][nt], 0, 0, 0);
        }
      }
      const bool need_mask = (kv0 + 63 > wrow0);
      // ---- P = exp2(S*SC); write to per-wave LDS (quad-swizzled cols) ----
#pragma unroll
      for (int mt = 0; mt < 2; ++mt)
#pragma unroll
        for (int r = 0; r < 4; ++r) {
          const int row = wrow0 + mt * 16 + quad * 4 + r;
          u16t* prow = &lPw[(mt * 16 + quad * 4 + r) * PSTR];
#pragma unroll
          for (int nt = 0; nt < 4; ++nt) {
            float pv = __builtin_amdgcn_exp2f(sacc[mt][nt][r] * SC);
            if (need_mask && (kv0 + nt * 16 + l16 > row)) pv = 0.f;
            prow[(nt * 16 + l16) ^ (quad << 3)] = f2bf(pv);
          }
        }
      // Drain LDS writes before same-wave readback (intra-wave RAW).
      __asm__ __volatile__("s_waitcnt lgkmcnt(0)" ::: "memory");
      // ---- O += P V ; l += P * ones ----
#pragma unroll
      for (int kk = 0; kk < 2; ++kk) {
        const int colb = (kk * 32 + quad * 8) ^ pswz;
        bf16x8 pf[2];
#pragma unroll
        for (int qn = 0; qn < 2; ++qn)
          pf[qn] = *(const bf16x8*)&lPw[(qn * 16 + l16) * PSTR + colb];
#pragma unroll
        for (int qn = 0; qn < 2; ++qn)
          lacc[qn] = __builtin_amdgcn_mfma_f32_16x16x32_bf16(pf[qn], ones, lacc[qn], 0, 0, 0);
#pragma unroll
        for (int dn = 0; dn < 4; ++dn) {
          bf16x8 vf = *(const bf16x8*)&lVt[(dn * 16 + l16) * VSTR + colb];
#pragma unroll
          for (int qn = 0; qn < 2; ++qn)
            oacc[qn][dn] = __builtin_amdgcn_mfma_f32_16x16x32_bf16(pf[qn], vf, oacc[qn][dn], 0, 0, 0);
        }
      }
    }
    BARRIER_LGKM();                      // all reads of LDS tile kv0 done
    if (havenext) STORE_TILE();          // overwrite with tile kv0+64
  }

  // ---- epilogue: PLAIN coalesced stores to this block's private slot ----
  // (waves whose rows are entirely masked store their zero accumulators;
  //  normalize sums all slots, so zeros are required, not optional)
  {
    float* po = pO + (((size_t)h * SLOTS + slot) * 128) * HD;
    float* pl = pL + ((size_t)h * SLOTS + slot) * 128;
#pragma unroll
    for (int qn = 0; qn < 2; ++qn) {
#pragma unroll
      for (int r = 0; r < 4; ++r) {
        const int ql = wid * 32 + qn * 16 + quad * 4 + r;   // local q row
#pragma unroll
        for (int dn = 0; dn < 4; ++dn)
          po[(size_t)ql * HD + dn * 16 + l16] = oacc[qn][dn][r];
        if (l16 == 0) pl[ql] = lacc[qn][r];
      }
    }
  }
#undef LOAD_TILE
#undef STORE_TILE
}

// ---------------------------------------------------------------------------
// y[q][c] = sum_s pO[h][slot(qt)+s][q&127][d] / sum_s pL[...]
// ---------------------------------------------------------------------------
__global__ __launch_bounds__(256) void attn_normalize(const float* __restrict__ pO,
                                                      const float* __restrict__ pL,
                                                      u16t* __restrict__ y) {
  const int i = blockIdx.x * 256 + threadIdx.x;   // over T*C
  const int q = i / CDIM, c = i % CDIM;
  const int h = c >> 6, d = c & 63;
  const int qt = q >> 7, ql = q & 127;
  const int g = qt >> 3, rr = qt & 7;
  const int base = qt + 4 * g * (g - 1) + rr * g;
  const int ns = g + 1;                            // ceil((qt+1)/8)
  float o = 0.f, l = 0.f;
  for (int s = 0; s < ns; ++s) {
    const size_t sl = (size_t)h * SLOTS + base + s;
    o += pO[(sl * 128 + ql) * HD + d];
    l += pL[sl * 128 + ql];
  }
  y[i] = f2bf(o / l);
}

// ---------------------------------------------------------------------------
extern "C" void kernel_launch(void* const* d_in, const int* in_sizes, int n_in,
                              void* d_out, int out_size, void* d_ws, size_t ws_size,
                              hipStream_t stream) {
  const void* x     = d_in[0];
  // d_in[1] = mask (unused — causal mask applied analytically)
  const void* Wqkv  = d_in[2];
  const void* bqkv  = d_in[3];
  const void* Wproj = d_in[4];
  const void* bproj = d_in[5];

  u16t* qkv    = (u16t*)d_ws;                     // [4096][2304] bf16
  u16t* ybuf   = qkv    + (size_t)T_SEQ * C3;     // [4096][768]  bf16
  u16t* WqkvT  = ybuf   + (size_t)T_SEQ * CDIM;   // [2304][768]  bf16
  u16t* WprojT = WqkvT  + (size_t)C3 * CDIM;      // [768][768]   bf16
  u16t* xb     = WprojT + (size_t)CDIM * CDIM;    // [4096][768]  bf16
  float* pO    = (float*)(xb + (size_t)T_SEQ * CDIM);  // [12][80][128][64] f32
  float* pL    = pO + (size_t)NH * SLOTS * 128 * HD;   // [12][80][128]     f32
  int*  flag   = (int*)(pL + (size_t)NH * SLOTS * 128);

  detect_dtype<<<1, 256, 0, stream>>>((const u16t*)x, flag);
  convert_to_bf16<<<1024, 256, 0, stream>>>(x, xb, T_SEQ * CDIM, flag);
  transpose_to_bf16<<<dim3(C3 / 32, CDIM / 32), dim3(32, 8), 0, stream>>>(
      Wqkv, WqkvT, CDIM, C3, flag);
  transpose_to_bf16<<<dim3(CDIM / 32, CDIM / 32), dim3(32, 8), 0, stream>>>(
      Wproj, WprojT, CDIM, CDIM, flag);
  gemm_bt_bias<<<dim3(C3 / 128, T_SEQ / 128), 256, 0, stream>>>(
      xb, WqkvT, bqkv, qkv, T_SEQ, C3, CDIM, flag, 0);
  attn_partial<<<dim3(T_SEQ / STRIP_KV, T_SEQ / 128, NH), 256, 0, stream>>>(
      qkv, pO, pL);
  attn_normalize<<<(T_SEQ * CDIM) / 256, 256, 0, stream>>>(pO, pL, ybuf);
  gemm_bt_bias<<<dim3(CDIM / 128, T_SEQ / 128), 256, 0, stream>>>(
      ybuf, WprojT, bproj, d_out, T_SEQ, CDIM, CDIM, flag, 1);
}